// Round 3
// baseline (1967.405 us; speedup 1.0000x reference)
//
#include <hip/hip_runtime.h>
#include <math.h>

#define Bb 64
#define Ss 64
#define Hh 1024
#define Vv 32000
#define RD 4032     // 63*64 decoder rows
#define RP 4096     // padded rows
#define NT4 4096    // 4*H
#define ENC_NBLK 128

typedef unsigned short u16;
typedef __attribute__((ext_vector_type(8))) short bf16x8;
typedef __attribute__((ext_vector_type(4))) float f32x4;

#define MFMA(a, b, c) __builtin_amdgcn_mfma_f32_16x16x32_bf16(a, b, c, 0, 0, 0)

__device__ __forceinline__ u16 f2b(float f) {
  union { float f; unsigned u; } v; v.f = f;
  unsigned r = v.u + 0x7fffu + ((v.u >> 16) & 1u);
  return (u16)(r >> 16);
}
__device__ __forceinline__ float b2f(u16 b) {
  union { unsigned u; float f; } v; v.u = ((unsigned)b) << 16; return v.f;
}
__device__ __forceinline__ float sigf(float x) { return 1.f / (1.f + expf(-x)); }

__device__ __forceinline__ void gll16(const void* g, void* l) {
  __builtin_amdgcn_global_load_lds(
      (const __attribute__((address_space(1))) unsigned int*)g,
      (__attribute__((address_space(3))) unsigned int*)l, 16, 0, 0);
}

__global__ void k_fail(float* out) { out[0] = 1e30f; }

// ---- f32 -> bf16 convert (vector4) ----
__global__ void k_cvt(const float* __restrict__ in, u16* __restrict__ out, int n4) {
  int i = blockIdx.x * blockDim.x + threadIdx.x;
  const int st = gridDim.x * blockDim.x;
  for (; i < n4; i += st) {
    float4 v = ((const float4*)in)[i];
    ushort4 o; o.x = f2b(v.x); o.y = f2b(v.y); o.z = f2b(v.z); o.w = f2b(v.w);
    ((ushort4*)out)[i] = o;
  }
}

// ---- embedding gather -> bf16 rows (row r = step*64 + b), 256 thr * 4 elems ----
__global__ void k_gather(const int* __restrict__ tok, const float* __restrict__ emb,
                         u16* __restrict__ outp, int nstep) {
  const int r = blockIdx.x;
  const int step = r >> 6, b = r & 63;
  const int idx = (step < nstep) ? tok[b * 64 + step] : 0;
  const float4 v = ((const float4*)(emb + (size_t)idx * Hh))[threadIdx.x];
  ushort4 o; o.x = f2b(v.x); o.y = f2b(v.y); o.z = f2b(v.z); o.w = f2b(v.w);
  ((ushort4*)(outp + (size_t)r * Hh))[threadIdx.x] = o;
}

// ---- generic bf16 MFMA GEMM: C[M,N] = A[M,K] @ B[N,K]^T (+bias)(+tanh)
// global_load_lds width-16 staging, 128x128 tile, BK=64, XCD-swizzled blocks.
// EPI==0: write C.  EPI==2: fused per-row (max,sumexp) partials per 64-col half-tile.
template<int EPI>
__global__ __launch_bounds__(256)
void k_gemm(const u16* __restrict__ A, const u16* __restrict__ Bm,
            float* __restrict__ C, int M, int N, int K,
            const float* __restrict__ bias, int act,
            float* __restrict__ pmax, float* __restrict__ psum, int ncols) {
  __shared__ __align__(16) u16 As[128 * 64];
  __shared__ __align__(16) u16 Bs[128 * 64];
  const int tid = threadIdx.x;
  const int wave = tid >> 6, lane = tid & 63;
  const int l15 = lane & 15, lhi = lane >> 4;
  int bx = blockIdx.x, by = blockIdx.y;
  {
    const int nwg = gridDim.x * gridDim.y;
    if ((nwg & 7) == 0) {
      int flat = by * gridDim.x + bx;
      const int q = nwg >> 3;
      flat = (flat & 7) * q + (flat >> 3);
      bx = flat % gridDim.x; by = flat / gridDim.x;
    }
  }
  const int m0 = by * 128, n0 = bx * 128;
  const int wm = (wave >> 1) * 64, wn = (wave & 1) * 64;
  f32x4 acc[4][4] = {};

  // staging geometry: wave stages rows [wave*32, wave*32+32), 8 rows per gll inst
  const int srow = wave * 32 + (lane >> 3);   // + q*8
  const int scolb = (lane & 7) * 16;          // byte offset within 128B row

  for (int k0 = 0; k0 < K; k0 += 64) {
    __syncthreads();
#pragma unroll
    for (int q = 0; q < 4; ++q) {
      const int r = srow + q * 8;
      int ra = m0 + r; ra = (ra < M) ? ra : (M - 1);
      const char* ga = (const char*)(A + (size_t)ra * K + k0) + scolb;
      const char* gb = (const char*)(Bm + (size_t)(n0 + r) * K + k0) + scolb;
      char* lA = (char*)As + (wave * 32 + q * 8) * 128;
      char* lB = (char*)Bs + (wave * 32 + q * 8) * 128;
      gll16(ga, lA);
      gll16(gb, lB);
    }
    __syncthreads();
#pragma unroll
    for (int kk = 0; kk < 2; ++kk) {
      const int ko = kk * 32 + lhi * 8;
      bf16x8 af[4], bfr[4];
#pragma unroll
      for (int i = 0; i < 4; ++i) af[i] = *(const bf16x8*)(As + (wm + i * 16 + l15) * 64 + ko);
#pragma unroll
      for (int j = 0; j < 4; ++j) bfr[j] = *(const bf16x8*)(Bs + (wn + j * 16 + l15) * 64 + ko);
#pragma unroll
      for (int i = 0; i < 4; ++i)
#pragma unroll
        for (int j = 0; j < 4; ++j)
          acc[i][j] = MFMA(af[i], bfr[j], acc[i][j]);
    }
  }

  if (EPI == 0) {
#pragma unroll
    for (int i = 0; i < 4; ++i) {
      const int gr = m0 + wm + i * 16 + lhi * 4;
#pragma unroll
      for (int j = 0; j < 4; ++j) {
        const int gc = n0 + wn + j * 16 + l15;
        const float bv = bias ? bias[gc] : 0.f;
#pragma unroll
        for (int rr = 0; rr < 4; ++rr) {
          float v = acc[i][j][rr] + bv;
          if (act) v = tanhf(v);
          C[(size_t)(gr + rr) * N + gc] = v;
        }
      }
    }
  } else {
    float bj[4];
#pragma unroll
    for (int j = 0; j < 4; ++j) bj[j] = bias[n0 + wn + j * 16 + l15];
    const int pc = bx * 2 + (wn ? 1 : 0);  // 64-col half-tile column index
#pragma unroll
    for (int i = 0; i < 4; ++i) {
#pragma unroll
      for (int rr = 0; rr < 4; ++rr) {
        float v0 = acc[i][0][rr] + bj[0];
        float v1 = acc[i][1][rr] + bj[1];
        float v2 = acc[i][2][rr] + bj[2];
        float v3 = acc[i][3][rr] + bj[3];
        float m = fmaxf(fmaxf(v0, v1), fmaxf(v2, v3));
#pragma unroll
        for (int d = 1; d < 16; d <<= 1) m = fmaxf(m, __shfl_xor(m, d, 64));
        float s = __expf(v0 - m) + __expf(v1 - m) + __expf(v2 - m) + __expf(v3 - m);
#pragma unroll
        for (int d = 1; d < 16; d <<= 1) s += __shfl_xor(s, d, 64);
        if (l15 == 0) {
          const int grow = m0 + wm + i * 16 + lhi * 4 + rr;
          pmax[(size_t)grow * ncols + pc] = m;
          psum[(size_t)grow * ncols + pc] = s;
        }
      }
    }
  }
}

// ---- persistent encoder: all 64 LSTM steps in one kernel.
// 128 blocks x 256 thr; block owns 8 h-cols (32 gate rows); W slice in LDS
// (XOR-swizzled), c-state in LDS; h read from hxl (L2/L3) into MFMA A-frags.
// Grid barrier: per-block flag array (64B-padded slots), read-only polling —
// no single-counter atomic storm.
__global__ __launch_bounds__(256, 1)
void k_enc_all(const u16* __restrict__ Wb, const float* __restrict__ gx,
               const float* __restrict__ b_ih, const float* __restrict__ b_hh,
               u16* __restrict__ hxl, float* __restrict__ c_out, int* flags) {
  __shared__ __align__(16) u16 Ws[32 * 1024];  // 64KB, byte-XOR swizzled per row
  __shared__ float Gs[64 * 33];                // padded stride vs bank conflicts
  __shared__ float Cs[512];
  __shared__ float bsum[32];
  const int tid = threadIdx.x;
  const int wave = tid >> 6, lane = tid & 63;
  const int l15 = lane & 15, lhi = lane >> 4;
  const int c0 = blockIdx.x * 8;

  for (int i = tid; i < 32 * 128; i += 256) {
    const int rr = i >> 7, ck = i & 127;  // row rr, 16B chunk ck
    const int wrow = (rr >> 3) * Hh + c0 + (rr & 7);
    const int bo = (ck * 16) ^ ((rr & 7) << 4);
    *(bf16x8*)((char*)Ws + rr * 2048 + bo) = *(const bf16x8*)(Wb + (size_t)wrow * Hh + ck * 8);
  }
  if (tid < 32) {
    const int col = (tid >> 3) * Hh + c0 + (tid & 7);
    bsum[tid] = b_ih[col] + b_hh[col];
  }
  for (int i = tid; i < 512; i += 256) Cs[i] = 0.f;
  __syncthreads();

  for (int s = 0; s < 64; ++s) {
    // prefetch this step's x-gates into registers (independent of h / barrier)
    float gpre[2][4];
#pragma unroll
    for (int u = 0; u < 2; ++u) {
      const int e = tid + u * 256;
      const int b = e >> 3, hc = e & 7;
      const float* p = gx + (size_t)(s * 64 + b) * NT4 + c0 + hc;
      gpre[u][0] = p[0]; gpre[u][1] = p[Hh]; gpre[u][2] = p[2 * Hh]; gpre[u][3] = p[3 * Hh];
    }

    f32x4 a0a = {}, a0b = {}, a1a = {}, a1b = {};
    if (s > 0) {
      const u16* ap = hxl + ((size_t)(s - 1) * 64 + wave * 16 + l15) * Hh;
      const char* wsb = (const char*)Ws;
      const int xr = (l15 & 7) << 4;
#pragma unroll 8
      for (int kf = 0; kf < 32; ++kf) {
        const int k = kf * 32 + lhi * 8;
        const bf16x8 af = *(const bf16x8*)(ap + k);
        const int bo = (k * 2) ^ xr;
        const bf16x8 b0 = *(const bf16x8*)(wsb + l15 * 2048 + bo);
        const bf16x8 b1 = *(const bf16x8*)(wsb + (16 + l15) * 2048 + bo);
        if (kf & 1) { a0b = MFMA(af, b0, a0b); a1b = MFMA(af, b1, a1b); }
        else        { a0a = MFMA(af, b0, a0a); a1a = MFMA(af, b1, a1a); }
      }
    }
#pragma unroll
    for (int r = 0; r < 4; ++r) {
      Gs[(wave * 16 + lhi * 4 + r) * 33 + l15] = a0a[r] + a0b[r];
      Gs[(wave * 16 + lhi * 4 + r) * 33 + 16 + l15] = a1a[r] + a1b[r];
    }
    __syncthreads();
#pragma unroll
    for (int u = 0; u < 2; ++u) {
      const int e = tid + u * 256;
      const int b = e >> 3, hc = e & 7;
      const float gi = Gs[b * 33 + hc]      + gpre[u][0] + bsum[hc];
      const float gf = Gs[b * 33 + 8 + hc]  + gpre[u][1] + bsum[8 + hc];
      const float gg = Gs[b * 33 + 16 + hc] + gpre[u][2] + bsum[16 + hc];
      const float go = Gs[b * 33 + 24 + hc] + gpre[u][3] + bsum[24 + hc];
      const float cn = sigf(gf) * Cs[e] + sigf(gi) * tanhf(gg);
      const float hv = sigf(go) * tanhf(cn);
      Cs[e] = cn;
      hxl[((size_t)s * 64 + b) * Hh + c0 + hc] = f2b(hv);
    }
    // ---- flag-array grid barrier ----
    __syncthreads();
    if (tid == 0) {
      __threadfence();  // release: write back this block's h stores
      __hip_atomic_store(flags + blockIdx.x * 16, s + 1,
                         __ATOMIC_RELAXED, __HIP_MEMORY_SCOPE_AGENT);
    }
    if (tid < ENC_NBLK) {
      while (__hip_atomic_load(flags + tid * 16,
                               __ATOMIC_RELAXED, __HIP_MEMORY_SCOPE_AGENT) < s + 1) {
        __builtin_amdgcn_s_sleep(1);
      }
    }
    __syncthreads();
    __threadfence();  // acquire: invalidate before reading other blocks' h
  }
  for (int e = tid; e < 512; e += 256)
    c_out[(e >> 3) * Hh + c0 + (e & 7)] = Cs[e];
}

// ---- decoder cell (non-recurrent): gates = G[r] + dbase[b] + b_ih + b_hh
__global__ void k_dec_cell(const float* __restrict__ G, const float* __restrict__ dbase,
                           const float* __restrict__ cT, const float* __restrict__ b_ih,
                           const float* __restrict__ b_hh, u16* __restrict__ Acat) {
  const int idx = blockIdx.x * 256 + threadIdx.x;
  if (idx >= RD * Hh) return;
  const int r = idx >> 10, nh = idx & 1023;
  const int b = r & 63;
  const size_t gr = (size_t)r * NT4;
  const size_t br = (size_t)b * NT4;
  const float gi = G[gr + nh]        + dbase[br + nh]        + b_ih[nh]        + b_hh[nh];
  const float gf = G[gr + Hh + nh]   + dbase[br + Hh + nh]   + b_ih[Hh + nh]   + b_hh[Hh + nh];
  const float gg = G[gr + 2*Hh + nh] + dbase[br + 2*Hh + nh] + b_ih[2*Hh + nh] + b_hh[2*Hh + nh];
  const float go = G[gr + 3*Hh + nh] + dbase[br + 3*Hh + nh] + b_ih[3*Hh + nh] + b_hh[3*Hh + nh];
  const float cn = sigf(gf) * cT[b * Hh + nh] + sigf(gi) * tanhf(gg);
  const float hv = sigf(go) * tanhf(cn);
  Acat[(size_t)r * 2048 + Hh + nh] = f2b(hv);
}

// ---- fused attention per (t,b): scores + masked softmax + content -> A_cat[:, :H]
__global__ __launch_bounds__(256)
void k_attn(u16* Acat, const u16* __restrict__ hxl, const int* __restrict__ src) {
  __shared__ float qs[Hh];
  __shared__ float sc[Ss];
  const int r = blockIdx.x;  // t*64 + b
  const int b = r & 63;
  const int tid = threadIdx.x, wave = tid >> 6, lane = tid & 63;
  for (int h = tid; h < Hh; h += 256) qs[h] = b2f(Acat[(size_t)r * 2048 + Hh + h]);
  __syncthreads();
  for (int sub = 0; sub < 16; ++sub) {
    const int ss = wave * 16 + sub;
    const ushort4* hp4 = (const ushort4*)(hxl + ((size_t)ss * Bb + b) * Hh);
    float p = 0.f;
#pragma unroll
    for (int q = 0; q < 4; ++q) {
      const int i4 = lane + 64 * q;
      const ushort4 v = hp4[i4];
      p += qs[i4 * 4 + 0] * b2f(v.x) + qs[i4 * 4 + 1] * b2f(v.y)
         + qs[i4 * 4 + 2] * b2f(v.z) + qs[i4 * 4 + 3] * b2f(v.w);
    }
#pragma unroll
    for (int d = 1; d < 64; d <<= 1) p += __shfl_xor(p, d, 64);
    if (lane == 0) sc[ss] = (src[b * 64 + ss] != 0) ? p : -INFINITY;
  }
  __syncthreads();
  if (wave == 0) {
    const float v = sc[lane];
    float m = v;
#pragma unroll
    for (int d = 1; d < 64; d <<= 1) m = fmaxf(m, __shfl_xor(m, d, 64));
    const float e = __expf(v - m);
    float ssum = e;
#pragma unroll
    for (int d = 1; d < 64; d <<= 1) ssum += __shfl_xor(ssum, d, 64);
    sc[lane] = e / ssum;
  }
  __syncthreads();
  float4 a4 = {0.f, 0.f, 0.f, 0.f};
  for (int s2 = 0; s2 < 64; ++s2) {
    const float a = sc[s2];
    const ushort4 v = *(const ushort4*)(hxl + ((size_t)s2 * Bb + b) * Hh + tid * 4);
    a4.x += a * b2f(v.x); a4.y += a * b2f(v.y);
    a4.z += a * b2f(v.z); a4.w += a * b2f(v.w);
  }
  u16* dst = Acat + (size_t)r * 2048 + tid * 4;
  dst[0] = f2b(a4.x); dst[1] = f2b(a4.y); dst[2] = f2b(a4.z); dst[3] = f2b(a4.w);
}

// ---- combine lse partials: one wave per row
__global__ void k_lse(const float* __restrict__ pmax, const float* __restrict__ psum,
                      float* __restrict__ lse, int ncols) {
  const int r = blockIdx.x * 4 + (threadIdx.x >> 6);
  const int lane = threadIdx.x & 63;
  if (r >= RD) return;
  float m = -INFINITY;
  for (int i = lane; i < ncols; i += 64) m = fmaxf(m, pmax[(size_t)r * ncols + i]);
#pragma unroll
  for (int d = 1; d < 64; d <<= 1) m = fmaxf(m, __shfl_xor(m, d, 64));
  float s = 0.f;
  for (int i = lane; i < ncols; i += 64)
    s += psum[(size_t)r * ncols + i] * __expf(pmax[(size_t)r * ncols + i] - m);
#pragma unroll
  for (int d = 1; d < 64; d <<= 1) s += __shfl_xor(s, d, 64);
  if (lane == 0) lse[r] = m + logf(s);
}

// ---- target logit: one wave per row (fp32 dot)
__global__ void k_tlogit(const float* __restrict__ hx_att, const int* __restrict__ target,
                         const float* __restrict__ W, const float* __restrict__ bo,
                         float* __restrict__ outp) {
  const int r = blockIdx.x * 4 + (threadIdx.x >> 6);
  const int lane = threadIdx.x & 63;
  if (r >= RD) return;
  const int t = r >> 6, b = r & 63;
  const int w = target[b * 64 + t + 1];
  const float* a = hx_att + (size_t)r * Hh;
  const float* wr = W + (size_t)w * Hh;
  float p = 0.f;
  for (int h = lane; h < Hh; h += 64) p += a[h] * wr[h];
#pragma unroll
  for (int d = 1; d < 64; d <<= 1) p += __shfl_xor(p, d, 64);
  if (lane == 0) outp[r] = p + bo[w];
}

// ---- final reduction -> scalar loss
__global__ void k_final(const float* __restrict__ lse, const float* __restrict__ tl,
                        const int* __restrict__ target, float* __restrict__ out) {
  const int t = threadIdx.x;  // 64 threads, t<63 active
  float ps = 0.f;
  if (t < 63) {
    float sn = 0.f, cnt = 0.f;
    for (int b = 0; b < 64; ++b) {
      const int r = t * 64 + b;
      const int w = target[b * 64 + t + 1];
      if (w != 0) { sn += lse[r] - tl[r]; cnt += 1.f; }
    }
    ps = sn / fmaxf(cnt, 1.f);
  }
#pragma unroll
  for (int d = 1; d < 64; d <<= 1) ps += __shfl_xor(ps, d, 64);
  if (t == 0) out[0] = ps;
}

extern "C" void kernel_launch(void* const* d_in, const int* in_sizes, int n_in,
                              void* d_out, int out_size, void* d_ws, size_t ws_size,
                              hipStream_t stream) {
  const int*   source   = (const int*)d_in[0];
  const int*   target   = (const int*)d_in[1];
  const float* emb_src  = (const float*)d_in[2];
  const float* emb_tgt  = (const float*)d_in[3];
  const float* W_ih_enc = (const float*)d_in[4];
  const float* W_hh_enc = (const float*)d_in[5];
  const float* b_ih_enc = (const float*)d_in[6];
  const float* b_hh_enc = (const float*)d_in[7];
  const float* W_ih_dec = (const float*)d_in[8];
  const float* W_hh_dec = (const float*)d_in[9];
  const float* b_ih_dec = (const float*)d_in[10];
  const float* b_hh_dec = (const float*)d_in[11];
  const float* W_att    = (const float*)d_in[12];
  const float* b_att    = (const float*)d_in[13];
  const float* W_out    = (const float*)d_in[14];
  const float* b_out    = (const float*)d_in[15];
  float* out = (float*)d_out;

  char* base = (char*)d_ws;
  size_t off = 0;
  auto alloc = [&](size_t bytes) -> void* {
    void* r = base + off; off += (bytes + 255) & ~(size_t)255; return r;
  };
  u16*   wb_ih_enc = (u16*)alloc((size_t)NT4 * Hh * 2);
  u16*   wb_hh_enc = (u16*)alloc((size_t)NT4 * Hh * 2);
  u16*   wb_ih_dec = (u16*)alloc((size_t)NT4 * Hh * 2);
  u16*   wb_hh_dec = (u16*)alloc((size_t)NT4 * Hh * 2);
  u16*   wb_att    = (u16*)alloc((size_t)Hh * 2048 * 2);
  u16*   wb_out    = (u16*)alloc((size_t)Vv * Hh * 2);
  u16*   x_src_b   = (u16*)alloc((size_t)RP * Hh * 2);
  u16*   x_dec_b   = (u16*)alloc((size_t)RP * Hh * 2);
  float* gates     = (float*)alloc((size_t)RP * NT4 * 4);
  u16*   hxl       = (u16*)alloc((size_t)Ss * Bb * Hh * 2);
  float* c_enc     = (float*)alloc((size_t)Bb * Hh * 4);
  float* dbase     = (float*)alloc((size_t)128 * NT4 * 4);
  u16*   Acat      = (u16*)alloc((size_t)RP * 2048 * 2);
  float* hx_att    = (float*)alloc((size_t)RP * Hh * 4);
  u16*   hx_att_b  = (u16*)alloc((size_t)RP * Hh * 2);
  float* pmax      = (float*)alloc((size_t)RP * 500 * 4);
  float* psum      = (float*)alloc((size_t)RP * 500 * 4);
  float* lse       = (float*)alloc((size_t)RD * 4);
  float* tlog      = (float*)alloc((size_t)RD * 4);
  int*   flags     = (int*)alloc(ENC_NBLK * 64);

  if (off > ws_size) { k_fail<<<1, 1, 0, stream>>>(out); return; }

  // weights -> bf16
  k_cvt<<<2048, 256, 0, stream>>>(W_ih_enc, wb_ih_enc, NT4 * Hh / 4);
  k_cvt<<<2048, 256, 0, stream>>>(W_hh_enc, wb_hh_enc, NT4 * Hh / 4);
  k_cvt<<<2048, 256, 0, stream>>>(W_ih_dec, wb_ih_dec, NT4 * Hh / 4);
  k_cvt<<<2048, 256, 0, stream>>>(W_hh_dec, wb_hh_dec, NT4 * Hh / 4);
  k_cvt<<<2048, 256, 0, stream>>>(W_att, wb_att, Hh * 2048 / 4);
  k_cvt<<<2048, 256, 0, stream>>>(W_out, wb_out, Vv * Hh / 4);

  hipMemsetAsync(Acat, 0, (size_t)RP * 2048 * 2, stream);
  hipMemsetAsync(flags, 0, ENC_NBLK * 64, stream);

  // embedding gathers
  k_gather<<<RP, 256, 0, stream>>>(source, emb_src, x_src_b, 64);
  k_gather<<<RP, 256, 0, stream>>>(target, emb_tgt, x_dec_b, 63);

  // encoder: x-gates pre-GEMM, then ONE persistent kernel for all 64 steps
  k_gemm<0><<<dim3(32, 32), 256, 0, stream>>>(x_src_b, wb_ih_enc, gates, RP, NT4, Hh,
                                              nullptr, 0, nullptr, nullptr, 0);
  k_enc_all<<<ENC_NBLK, 256, 0, stream>>>(wb_hh_enc, gates, b_ih_enc, b_hh_enc,
                                          hxl, c_enc, flags);

  // decoder gates (reuse `gates`) + hT base + cell
  k_gemm<0><<<dim3(32, 32), 256, 0, stream>>>(x_dec_b, wb_ih_dec, gates, RP, NT4, Hh,
                                              nullptr, 0, nullptr, nullptr, 0);
  k_gemm<0><<<dim3(32, 1), 256, 0, stream>>>(hxl + (size_t)63 * Bb * Hh, wb_hh_dec, dbase,
                                             64, NT4, Hh, nullptr, 0, nullptr, nullptr, 0);
  k_dec_cell<<<(RD * Hh) / 256, 256, 0, stream>>>(gates, dbase, c_enc, b_ih_dec, b_hh_dec, Acat);

  // attention -> content into A_cat[:, :H]
  k_attn<<<RD, 256, 0, stream>>>(Acat, hxl, source);

  // hx_att = tanh(A_cat @ W_att^T + b_att), then bf16 copy
  k_gemm<0><<<dim3(8, 32), 256, 0, stream>>>(Acat, wb_att, hx_att, RP, Hh, 2048,
                                             b_att, 1, nullptr, nullptr, 0);
  k_cvt<<<2048, 256, 0, stream>>>(hx_att, hx_att_b, RP * Hh / 4);

  // vocab GEMM with fused lse partials
  k_gemm<2><<<dim3(250, 32), 256, 0, stream>>>(hx_att_b, wb_out, nullptr, RP, Vv, Hh,
                                               b_out, 0, pmax, psum, 500);
  k_lse<<<(RD + 3) / 4, 256, 0, stream>>>(pmax, psum, lse, 500);
  k_tlogit<<<(RD + 3) / 4, 256, 0, stream>>>(hx_att, target, W_out, b_out, tlog);
  k_final<<<1, 64, 0, stream>>>(lse, tlog, target, out);
}

// Round 4
// 1538.700 us; speedup vs baseline: 1.2786x; 1.2786x over previous
//
#include <hip/hip_runtime.h>
#include <math.h>

#define Bb 64
#define Ss 64
#define Hh 1024
#define Vv 32000
#define RD 4032     // 63*64 decoder rows
#define RP 4096     // padded rows
#define NT4 4096    // 4*H
#define ENC_NBLK 128

typedef unsigned short u16;
typedef unsigned long long u64;
typedef __attribute__((ext_vector_type(8))) short bf16x8;
typedef __attribute__((ext_vector_type(4))) float f32x4;

#define MFMA(a, b, c) __builtin_amdgcn_mfma_f32_16x16x32_bf16(a, b, c, 0, 0, 0)

__device__ __forceinline__ u16 f2b(float f) {
  union { float f; unsigned u; } v; v.f = f;
  unsigned r = v.u + 0x7fffu + ((v.u >> 16) & 1u);
  return (u16)(r >> 16);
}
__device__ __forceinline__ float b2f(u16 b) {
  union { unsigned u; float f; } v; v.u = ((unsigned)b) << 16; return v.f;
}
__device__ __forceinline__ float sigf(float x) { return 1.f / (1.f + expf(-x)); }

__device__ __forceinline__ void gll16(const void* g, void* l) {
  __builtin_amdgcn_global_load_lds(
      (const __attribute__((address_space(1))) unsigned int*)g,
      (__attribute__((address_space(3))) unsigned int*)l, 16, 0, 0);
}

__global__ void k_fail(float* out) { out[0] = 1e30f; }

// ---- f32 -> bf16 convert (vector4) ----
__global__ void k_cvt(const float* __restrict__ in, u16* __restrict__ out, int n4) {
  int i = blockIdx.x * blockDim.x + threadIdx.x;
  const int st = gridDim.x * blockDim.x;
  for (; i < n4; i += st) {
    float4 v = ((const float4*)in)[i];
    ushort4 o; o.x = f2b(v.x); o.y = f2b(v.y); o.z = f2b(v.z); o.w = f2b(v.w);
    ((ushort4*)out)[i] = o;
  }
}

// ---- embedding gather -> bf16 rows (row r = step*64 + b), 256 thr * 4 elems ----
__global__ void k_gather(const int* __restrict__ tok, const float* __restrict__ emb,
                         u16* __restrict__ outp, int nstep) {
  const int r = blockIdx.x;
  const int step = r >> 6, b = r & 63;
  const int idx = (step < nstep) ? tok[b * 64 + step] : 0;
  const float4 v = ((const float4*)(emb + (size_t)idx * Hh))[threadIdx.x];
  ushort4 o; o.x = f2b(v.x); o.y = f2b(v.y); o.z = f2b(v.z); o.w = f2b(v.w);
  ((ushort4*)(outp + (size_t)r * Hh))[threadIdx.x] = o;
}

// ---- generic bf16 MFMA GEMM: C[M,N] = A[M,K] @ B[N,K]^T (+bias)(+tanh)
// global_load_lds width-16 staging, 128x128 tile, BK=64, XCD-swizzled blocks.
// EPI==0: write C.  EPI==2: fused per-row (max,sumexp) partials per 64-col half-tile.
template<int EPI>
__global__ __launch_bounds__(256)
void k_gemm(const u16* __restrict__ A, const u16* __restrict__ Bm,
            float* __restrict__ C, int M, int N, int K,
            const float* __restrict__ bias, int act,
            float* __restrict__ pmax, float* __restrict__ psum, int ncols) {
  __shared__ __align__(16) u16 As[128 * 64];
  __shared__ __align__(16) u16 Bs[128 * 64];
  const int tid = threadIdx.x;
  const int wave = tid >> 6, lane = tid & 63;
  const int l15 = lane & 15, lhi = lane >> 4;
  int bx = blockIdx.x, by = blockIdx.y;
  {
    const int nwg = gridDim.x * gridDim.y;
    if ((nwg & 7) == 0) {
      int flat = by * gridDim.x + bx;
      const int q = nwg >> 3;
      flat = (flat & 7) * q + (flat >> 3);
      bx = flat % gridDim.x; by = flat / gridDim.x;
    }
  }
  const int m0 = by * 128, n0 = bx * 128;
  const int wm = (wave >> 1) * 64, wn = (wave & 1) * 64;
  f32x4 acc[4][4] = {};

  // staging geometry: wave stages rows [wave*32, wave*32+32), 8 rows per gll inst
  const int srow = wave * 32 + (lane >> 3);   // + q*8
  const int scolb = (lane & 7) * 16;          // byte offset within 128B row

  for (int k0 = 0; k0 < K; k0 += 64) {
    __syncthreads();
#pragma unroll
    for (int q = 0; q < 4; ++q) {
      const int r = srow + q * 8;
      int ra = m0 + r; ra = (ra < M) ? ra : (M - 1);
      const char* ga = (const char*)(A + (size_t)ra * K + k0) + scolb;
      const char* gb = (const char*)(Bm + (size_t)(n0 + r) * K + k0) + scolb;
      char* lA = (char*)As + (wave * 32 + q * 8) * 128;
      char* lB = (char*)Bs + (wave * 32 + q * 8) * 128;
      gll16(ga, lA);
      gll16(gb, lB);
    }
    __syncthreads();
#pragma unroll
    for (int kk = 0; kk < 2; ++kk) {
      const int ko = kk * 32 + lhi * 8;
      bf16x8 af[4], bfr[4];
#pragma unroll
      for (int i = 0; i < 4; ++i) af[i] = *(const bf16x8*)(As + (wm + i * 16 + l15) * 64 + ko);
#pragma unroll
      for (int j = 0; j < 4; ++j) bfr[j] = *(const bf16x8*)(Bs + (wn + j * 16 + l15) * 64 + ko);
#pragma unroll
      for (int i = 0; i < 4; ++i)
#pragma unroll
        for (int j = 0; j < 4; ++j)
          acc[i][j] = MFMA(af[i], bfr[j], acc[i][j]);
    }
  }

  if (EPI == 0) {
#pragma unroll
    for (int i = 0; i < 4; ++i) {
      const int gr = m0 + wm + i * 16 + lhi * 4;
#pragma unroll
      for (int j = 0; j < 4; ++j) {
        const int gc = n0 + wn + j * 16 + l15;
        const float bv = bias ? bias[gc] : 0.f;
#pragma unroll
        for (int rr = 0; rr < 4; ++rr) {
          float v = acc[i][j][rr] + bv;
          if (act) v = tanhf(v);
          C[(size_t)(gr + rr) * N + gc] = v;
        }
      }
    }
  } else {
    float bj[4];
#pragma unroll
    for (int j = 0; j < 4; ++j) bj[j] = bias[n0 + wn + j * 16 + l15];
    const int pc = bx * 2 + (wn ? 1 : 0);  // 64-col half-tile column index
#pragma unroll
    for (int i = 0; i < 4; ++i) {
#pragma unroll
      for (int rr = 0; rr < 4; ++rr) {
        float v0 = acc[i][0][rr] + bj[0];
        float v1 = acc[i][1][rr] + bj[1];
        float v2 = acc[i][2][rr] + bj[2];
        float v3 = acc[i][3][rr] + bj[3];
        float m = fmaxf(fmaxf(v0, v1), fmaxf(v2, v3));
#pragma unroll
        for (int d = 1; d < 16; d <<= 1) m = fmaxf(m, __shfl_xor(m, d, 64));
        float s = __expf(v0 - m) + __expf(v1 - m) + __expf(v2 - m) + __expf(v3 - m);
#pragma unroll
        for (int d = 1; d < 16; d <<= 1) s += __shfl_xor(s, d, 64);
        if (l15 == 0) {
          const int grow = m0 + wm + i * 16 + lhi * 4 + rr;
          pmax[(size_t)grow * ncols + pc] = m;
          psum[(size_t)grow * ncols + pc] = s;
        }
      }
    }
  }
}

// ---- persistent encoder: all 64 LSTM steps in one kernel.
// 128 blocks x 256 thr; block owns 8 h-cols (32 gate rows); W slice in LDS
// (XOR-swizzled), c-state in LDS.
// Cross-block h handoff: NO fences. h stores are write-through agent-scope
// atomics (nothing dirty in L2 -> no wbl2 needed); h loads are agent-scope
// atomic u64 loads (bypass L1/L2 -> always read coherence point). Flag
// store/poll are relaxed agent atomics; __syncthreads() drains vmcnt to
// order h stores before the flag store.
__global__ __launch_bounds__(256, 1)
void k_enc_all(const u16* __restrict__ Wb, const float* __restrict__ gx,
               const float* __restrict__ b_ih, const float* __restrict__ b_hh,
               u16* __restrict__ hxl, float* __restrict__ c_out, int* flags) {
  __shared__ __align__(16) u16 Ws[32 * 1024];  // 64KB, byte-XOR swizzled per row
  __shared__ float Gs[64 * 33];                // padded stride vs bank conflicts
  __shared__ float Cs[512];
  __shared__ float bsum[32];
  const int tid = threadIdx.x;
  const int wave = tid >> 6, lane = tid & 63;
  const int l15 = lane & 15, lhi = lane >> 4;
  const int c0 = blockIdx.x * 8;
  const int cb = tid >> 2, hp = (tid & 3) * 2;  // cell phase: batch cb, cols hp,hp+1

  for (int i = tid; i < 32 * 128; i += 256) {
    const int rr = i >> 7, ck = i & 127;  // row rr, 16B chunk ck
    const int wrow = (rr >> 3) * Hh + c0 + (rr & 7);
    const int bo = (ck * 16) ^ ((rr & 7) << 4);
    *(bf16x8*)((char*)Ws + rr * 2048 + bo) = *(const bf16x8*)(Wb + (size_t)wrow * Hh + ck * 8);
  }
  if (tid < 32) {
    const int col = (tid >> 3) * Hh + c0 + (tid & 7);
    bsum[tid] = b_ih[col] + b_hh[col];
  }
  for (int i = tid; i < 512; i += 256) Cs[i] = 0.f;
  __syncthreads();

  for (int s = 0; s < 64; ++s) {
    // prefetch this step's x-gates (independent of h / barrier)
    const float* gp = gx + (size_t)(s * 64 + cb) * NT4 + c0 + hp;
    float g0[4], g1[4];
    g0[0] = gp[0];      g1[0] = gp[1];
    g0[1] = gp[Hh];     g1[1] = gp[Hh + 1];
    g0[2] = gp[2 * Hh]; g1[2] = gp[2 * Hh + 1];
    g0[3] = gp[3 * Hh]; g1[3] = gp[3 * Hh + 1];

    f32x4 a0a = {}, a0b = {}, a1a = {}, a1b = {};
    if (s > 0) {
      const u64* apw = (const u64*)(hxl + ((size_t)(s - 1) * 64 + wave * 16 + l15) * Hh);
      const char* wsb = (const char*)Ws;
      const int xr = (l15 & 7) << 4;
#pragma unroll 8
      for (int kf = 0; kf < 32; ++kf) {
        const int k = kf * 32 + lhi * 8;
        const u64 q0 = __hip_atomic_load(apw + (k >> 2), __ATOMIC_RELAXED,
                                         __HIP_MEMORY_SCOPE_AGENT);
        const u64 q1 = __hip_atomic_load(apw + (k >> 2) + 1, __ATOMIC_RELAXED,
                                         __HIP_MEMORY_SCOPE_AGENT);
        union { u64 q[2]; bf16x8 v; } cv;
        cv.q[0] = q0; cv.q[1] = q1;
        const bf16x8 af = cv.v;
        const int bo = (k * 2) ^ xr;
        const bf16x8 b0 = *(const bf16x8*)(wsb + l15 * 2048 + bo);
        const bf16x8 b1 = *(const bf16x8*)(wsb + (16 + l15) * 2048 + bo);
        if (kf & 1) { a0b = MFMA(af, b0, a0b); a1b = MFMA(af, b1, a1b); }
        else        { a0a = MFMA(af, b0, a0a); a1a = MFMA(af, b1, a1a); }
      }
    }
#pragma unroll
    for (int r = 0; r < 4; ++r) {
      Gs[(wave * 16 + lhi * 4 + r) * 33 + l15] = a0a[r] + a0b[r];
      Gs[(wave * 16 + lhi * 4 + r) * 33 + 16 + l15] = a1a[r] + a1b[r];
    }
    __syncthreads();
    {
      const int e0 = cb * 8 + hp;
      const float gi0 = Gs[cb * 33 + hp]          + g0[0] + bsum[hp];
      const float gf0 = Gs[cb * 33 + 8 + hp]      + g0[1] + bsum[8 + hp];
      const float gg0 = Gs[cb * 33 + 16 + hp]     + g0[2] + bsum[16 + hp];
      const float go0 = Gs[cb * 33 + 24 + hp]     + g0[3] + bsum[24 + hp];
      const float gi1 = Gs[cb * 33 + hp + 1]      + g1[0] + bsum[hp + 1];
      const float gf1 = Gs[cb * 33 + 8 + hp + 1]  + g1[1] + bsum[8 + hp + 1];
      const float gg1 = Gs[cb * 33 + 16 + hp + 1] + g1[2] + bsum[16 + hp + 1];
      const float go1 = Gs[cb * 33 + 24 + hp + 1] + g1[3] + bsum[24 + hp + 1];
      const float cn0 = sigf(gf0) * Cs[e0]     + sigf(gi0) * tanhf(gg0);
      const float cn1 = sigf(gf1) * Cs[e0 + 1] + sigf(gi1) * tanhf(gg1);
      const float hv0 = sigf(go0) * tanhf(cn0);
      const float hv1 = sigf(go1) * tanhf(cn1);
      Cs[e0] = cn0; Cs[e0 + 1] = cn1;
      const unsigned pk = (unsigned)f2b(hv0) | ((unsigned)f2b(hv1) << 16);
      __hip_atomic_store((unsigned*)(hxl + ((size_t)s * 64 + cb) * Hh + c0 + hp), pk,
                         __ATOMIC_RELAXED, __HIP_MEMORY_SCOPE_AGENT);
    }
    // ---- fence-free flag barrier ----
    __syncthreads();  // drains vmcnt(0): h stores are at the coherence point
    if (tid == 0)
      __hip_atomic_store(flags + blockIdx.x * 16, s + 1,
                         __ATOMIC_RELAXED, __HIP_MEMORY_SCOPE_AGENT);
    if (tid < ENC_NBLK) {
      while (__hip_atomic_load(flags + tid * 16,
                               __ATOMIC_RELAXED, __HIP_MEMORY_SCOPE_AGENT) < s + 1) {
        __builtin_amdgcn_s_sleep(1);
      }
    }
    __syncthreads();
  }
  for (int e = tid; e < 512; e += 256)
    c_out[(e >> 3) * Hh + c0 + (e & 7)] = Cs[e];
}

// ---- decoder cell (non-recurrent): gates = G[r] + dbase[b] + b_ih + b_hh
__global__ void k_dec_cell(const float* __restrict__ G, const float* __restrict__ dbase,
                           const float* __restrict__ cT, const float* __restrict__ b_ih,
                           const float* __restrict__ b_hh, u16* __restrict__ Acat) {
  const int idx = blockIdx.x * 256 + threadIdx.x;
  if (idx >= RD * Hh) return;
  const int r = idx >> 10, nh = idx & 1023;
  const int b = r & 63;
  const size_t gr = (size_t)r * NT4;
  const size_t br = (size_t)b * NT4;
  const float gi = G[gr + nh]        + dbase[br + nh]        + b_ih[nh]        + b_hh[nh];
  const float gf = G[gr + Hh + nh]   + dbase[br + Hh + nh]   + b_ih[Hh + nh]   + b_hh[Hh + nh];
  const float gg = G[gr + 2*Hh + nh] + dbase[br + 2*Hh + nh] + b_ih[2*Hh + nh] + b_hh[2*Hh + nh];
  const float go = G[gr + 3*Hh + nh] + dbase[br + 3*Hh + nh] + b_ih[3*Hh + nh] + b_hh[3*Hh + nh];
  const float cn = sigf(gf) * cT[b * Hh + nh] + sigf(gi) * tanhf(gg);
  const float hv = sigf(go) * tanhf(cn);
  Acat[(size_t)r * 2048 + Hh + nh] = f2b(hv);
}

// ---- fused attention per (t,b): scores + masked softmax + content -> A_cat[:, :H]
__global__ __launch_bounds__(256)
void k_attn(u16* Acat, const u16* __restrict__ hxl, const int* __restrict__ src) {
  __shared__ float qs[Hh];
  __shared__ float sc[Ss];
  const int r = blockIdx.x;  // t*64 + b
  const int b = r & 63;
  const int tid = threadIdx.x, wave = tid >> 6, lane = tid & 63;
  for (int h = tid; h < Hh; h += 256) qs[h] = b2f(Acat[(size_t)r * 2048 + Hh + h]);
  __syncthreads();
  for (int sub = 0; sub < 16; ++sub) {
    const int ss = wave * 16 + sub;
    const ushort4* hp4 = (const ushort4*)(hxl + ((size_t)ss * Bb + b) * Hh);
    float p = 0.f;
#pragma unroll
    for (int q = 0; q < 4; ++q) {
      const int i4 = lane + 64 * q;
      const ushort4 v = hp4[i4];
      p += qs[i4 * 4 + 0] * b2f(v.x) + qs[i4 * 4 + 1] * b2f(v.y)
         + qs[i4 * 4 + 2] * b2f(v.z) + qs[i4 * 4 + 3] * b2f(v.w);
    }
#pragma unroll
    for (int d = 1; d < 64; d <<= 1) p += __shfl_xor(p, d, 64);
    if (lane == 0) sc[ss] = (src[b * 64 + ss] != 0) ? p : -INFINITY;
  }
  __syncthreads();
  if (wave == 0) {
    const float v = sc[lane];
    float m = v;
#pragma unroll
    for (int d = 1; d < 64; d <<= 1) m = fmaxf(m, __shfl_xor(m, d, 64));
    const float e = __expf(v - m);
    float ssum = e;
#pragma unroll
    for (int d = 1; d < 64; d <<= 1) ssum += __shfl_xor(ssum, d, 64);
    sc[lane] = e / ssum;
  }
  __syncthreads();
  float4 a4 = {0.f, 0.f, 0.f, 0.f};
  for (int s2 = 0; s2 < 64; ++s2) {
    const float a = sc[s2];
    const ushort4 v = *(const ushort4*)(hxl + ((size_t)s2 * Bb + b) * Hh + tid * 4);
    a4.x += a * b2f(v.x); a4.y += a * b2f(v.y);
    a4.z += a * b2f(v.z); a4.w += a * b2f(v.w);
  }
  u16* dst = Acat + (size_t)r * 2048 + tid * 4;
  dst[0] = f2b(a4.x); dst[1] = f2b(a4.y); dst[2] = f2b(a4.z); dst[3] = f2b(a4.w);
}

// ---- combine lse partials: one wave per row
__global__ void k_lse(const float* __restrict__ pmax, const float* __restrict__ psum,
                      float* __restrict__ lse, int ncols) {
  const int r = blockIdx.x * 4 + (threadIdx.x >> 6);
  const int lane = threadIdx.x & 63;
  if (r >= RD) return;
  float m = -INFINITY;
  for (int i = lane; i < ncols; i += 64) m = fmaxf(m, pmax[(size_t)r * ncols + i]);
#pragma unroll
  for (int d = 1; d < 64; d <<= 1) m = fmaxf(m, __shfl_xor(m, d, 64));
  float s = 0.f;
  for (int i = lane; i < ncols; i += 64)
    s += psum[(size_t)r * ncols + i] * __expf(pmax[(size_t)r * ncols + i] - m);
#pragma unroll
  for (int d = 1; d < 64; d <<= 1) s += __shfl_xor(s, d, 64);
  if (lane == 0) lse[r] = m + logf(s);
}

// ---- target logit: one wave per row (fp32 dot)
__global__ void k_tlogit(const float* __restrict__ hx_att, const int* __restrict__ target,
                         const float* __restrict__ W, const float* __restrict__ bo,
                         float* __restrict__ outp) {
  const int r = blockIdx.x * 4 + (threadIdx.x >> 6);
  const int lane = threadIdx.x & 63;
  if (r >= RD) return;
  const int t = r >> 6, b = r & 63;
  const int w = target[b * 64 + t + 1];
  const float* a = hx_att + (size_t)r * Hh;
  const float* wr = W + (size_t)w * Hh;
  float p = 0.f;
  for (int h = lane; h < Hh; h += 64) p += a[h] * wr[h];
#pragma unroll
  for (int d = 1; d < 64; d <<= 1) p += __shfl_xor(p, d, 64);
  if (lane == 0) outp[r] = p + bo[w];
}

// ---- final reduction -> scalar loss
__global__ void k_final(const float* __restrict__ lse, const float* __restrict__ tl,
                        const int* __restrict__ target, float* __restrict__ out) {
  const int t = threadIdx.x;  // 64 threads, t<63 active
  float ps = 0.f;
  if (t < 63) {
    float sn = 0.f, cnt = 0.f;
    for (int b = 0; b < 64; ++b) {
      const int r = t * 64 + b;
      const int w = target[b * 64 + t + 1];
      if (w != 0) { sn += lse[r] - tl[r]; cnt += 1.f; }
    }
    ps = sn / fmaxf(cnt, 1.f);
  }
#pragma unroll
  for (int d = 1; d < 64; d <<= 1) ps += __shfl_xor(ps, d, 64);
  if (t == 0) out[0] = ps;
}

extern "C" void kernel_launch(void* const* d_in, const int* in_sizes, int n_in,
                              void* d_out, int out_size, void* d_ws, size_t ws_size,
                              hipStream_t stream) {
  const int*   source   = (const int*)d_in[0];
  const int*   target   = (const int*)d_in[1];
  const float* emb_src  = (const float*)d_in[2];
  const float* emb_tgt  = (const float*)d_in[3];
  const float* W_ih_enc = (const float*)d_in[4];
  const float* W_hh_enc = (const float*)d_in[5];
  const float* b_ih_enc = (const float*)d_in[6];
  const float* b_hh_enc = (const float*)d_in[7];
  const float* W_ih_dec = (const float*)d_in[8];
  const float* W_hh_dec = (const float*)d_in[9];
  const float* b_ih_dec = (const float*)d_in[10];
  const float* b_hh_dec = (const float*)d_in[11];
  const float* W_att    = (const float*)d_in[12];
  const float* b_att    = (const float*)d_in[13];
  const float* W_out    = (const float*)d_in[14];
  const float* b_out    = (const float*)d_in[15];
  float* out = (float*)d_out;

  char* base = (char*)d_ws;
  size_t off = 0;
  auto alloc = [&](size_t bytes) -> void* {
    void* r = base + off; off += (bytes + 255) & ~(size_t)255; return r;
  };
  u16*   wb_ih_enc = (u16*)alloc((size_t)NT4 * Hh * 2);
  u16*   wb_hh_enc = (u16*)alloc((size_t)NT4 * Hh * 2);
  u16*   wb_ih_dec = (u16*)alloc((size_t)NT4 * Hh * 2);
  u16*   wb_hh_dec = (u16*)alloc((size_t)NT4 * Hh * 2);
  u16*   wb_att    = (u16*)alloc((size_t)Hh * 2048 * 2);
  u16*   wb_out    = (u16*)alloc((size_t)Vv * Hh * 2);
  u16*   x_src_b   = (u16*)alloc((size_t)RP * Hh * 2);
  u16*   x_dec_b   = (u16*)alloc((size_t)RP * Hh * 2);
  float* gates     = (float*)alloc((size_t)RP * NT4 * 4);
  u16*   hxl       = (u16*)alloc((size_t)Ss * Bb * Hh * 2);
  float* c_enc     = (float*)alloc((size_t)Bb * Hh * 4);
  float* dbase     = (float*)alloc((size_t)128 * NT4 * 4);
  u16*   Acat      = (u16*)alloc((size_t)RP * 2048 * 2);
  float* hx_att    = (float*)alloc((size_t)RP * Hh * 4);
  u16*   hx_att_b  = (u16*)alloc((size_t)RP * Hh * 2);
  float* pmax      = (float*)alloc((size_t)RP * 500 * 4);
  float* psum      = (float*)alloc((size_t)RP * 500 * 4);
  float* lse       = (float*)alloc((size_t)RD * 4);
  float* tlog      = (float*)alloc((size_t)RD * 4);
  int*   flags     = (int*)alloc(ENC_NBLK * 64);

  if (off > ws_size) { k_fail<<<1, 1, 0, stream>>>(out); return; }

  // weights -> bf16
  k_cvt<<<2048, 256, 0, stream>>>(W_ih_enc, wb_ih_enc, NT4 * Hh / 4);
  k_cvt<<<2048, 256, 0, stream>>>(W_hh_enc, wb_hh_enc, NT4 * Hh / 4);
  k_cvt<<<2048, 256, 0, stream>>>(W_ih_dec, wb_ih_dec, NT4 * Hh / 4);
  k_cvt<<<2048, 256, 0, stream>>>(W_hh_dec, wb_hh_dec, NT4 * Hh / 4);
  k_cvt<<<2048, 256, 0, stream>>>(W_att, wb_att, Hh * 2048 / 4);
  k_cvt<<<2048, 256, 0, stream>>>(W_out, wb_out, Vv * Hh / 4);

  hipMemsetAsync(Acat, 0, (size_t)RP * 2048 * 2, stream);
  hipMemsetAsync(flags, 0, ENC_NBLK * 64, stream);

  // embedding gathers
  k_gather<<<RP, 256, 0, stream>>>(source, emb_src, x_src_b, 64);
  k_gather<<<RP, 256, 0, stream>>>(target, emb_tgt, x_dec_b, 63);

  // encoder: x-gates pre-GEMM, then ONE persistent kernel for all 64 steps
  k_gemm<0><<<dim3(32, 32), 256, 0, stream>>>(x_src_b, wb_ih_enc, gates, RP, NT4, Hh,
                                              nullptr, 0, nullptr, nullptr, 0);
  k_enc_all<<<ENC_NBLK, 256, 0, stream>>>(wb_hh_enc, gates, b_ih_enc, b_hh_enc,
                                          hxl, c_enc, flags);

  // decoder gates (reuse `gates`) + hT base + cell
  k_gemm<0><<<dim3(32, 32), 256, 0, stream>>>(x_dec_b, wb_ih_dec, gates, RP, NT4, Hh,
                                              nullptr, 0, nullptr, nullptr, 0);
  k_gemm<0><<<dim3(32, 1), 256, 0, stream>>>(hxl + (size_t)63 * Bb * Hh, wb_hh_dec, dbase,
                                             64, NT4, Hh, nullptr, 0, nullptr, nullptr, 0);
  k_dec_cell<<<(RD * Hh) / 256, 256, 0, stream>>>(gates, dbase, c_enc, b_ih_dec, b_hh_dec, Acat);

  // attention -> content into A_cat[:, :H]
  k_attn<<<RD, 256, 0, stream>>>(Acat, hxl, source);

  // hx_att = tanh(A_cat @ W_att^T + b_att), then bf16 copy
  k_gemm<0><<<dim3(8, 32), 256, 0, stream>>>(Acat, wb_att, hx_att, RP, Hh, 2048,
                                             b_att, 1, nullptr, nullptr, 0);
  k_cvt<<<2048, 256, 0, stream>>>(hx_att, hx_att_b, RP * Hh / 4);

  // vocab GEMM with fused lse partials
  k_gemm<2><<<dim3(250, 32), 256, 0, stream>>>(hx_att_b, wb_out, nullptr, RP, Vv, Hh,
                                               b_out, 0, pmax, psum, 500);
  k_lse<<<(RD + 3) / 4, 256, 0, stream>>>(pmax, psum, lse, 500);
  k_tlogit<<<(RD + 3) / 4, 256, 0, stream>>>(hx_att, target, W_out, b_out, tlog);
  k_final<<<1, 64, 0, stream>>>(lse, tlog, target, out);
}